// Round 2
// 247.342 us; speedup vs baseline: 1.1048x; 1.1048x over previous
//
#include <hip/hip_runtime.h>
#include <math.h>

#define F 128
#define DEG 5
#define TM 128
#define MAXNORM_D 0.996          // (1 - 4e-3)/sqrt(c), c=1
#define MIN_NORM_D 1e-15

typedef float f32x4 __attribute__((ext_vector_type(4)));
typedef short s16x8 __attribute__((ext_vector_type(8)));

__device__ inline double atanh_clip(double v) {
    v = fmin(fmax(v, -1.0 + 1e-7), 1.0 - 1e-7);
    return atanh(v);
}

__device__ inline void load_lds16(const void* g, void* l) {
    __builtin_amdgcn_global_load_lds((const __attribute__((address_space(1))) void*)g,
                                     (__attribute__((address_space(3))) void*)l, 16, 0, 0);
}

// split fp32 v -> hi bf16 (round-half-up) + lo bf16 (trunc of exact residual); pack pairs
__device__ inline void split2(float v0, float v1, unsigned& hi, unsigned& lo) {
    unsigned b0 = __float_as_uint(v0), b1 = __float_as_uint(v1);
    unsigned h0 = (b0 + 0x8000u) >> 16;
    unsigned h1 = (b1 + 0x8000u) >> 16;
    float l0 = v0 - __uint_as_float(h0 << 16);
    float l1 = v1 - __uint_as_float(h1 << 16);
    hi = h0 | (h1 << 16);
    lo = (__float_as_uint(l0) >> 16) | (__float_as_uint(l1) & 0xFFFF0000u);
}

// ---------------------------------------------------------------- K0: pack W into B-fragment order
// 2048 slots: Wfh/Wfl[(c*8+tp)*64+lane] = 8 bf16: f = tp*16+(lane&15), k = c*32+(lane>>4)*8 + j
// Bakes the MFMA B-layout into the GLOBAL array so k_gemm stages it with linear
// global_load_lds and reads it with lane-contiguous (conflict-free) ds_read_b128.
// GRID MUST BE 8 BLOCKS (2048 threads): tid>=2048 would read past W (64 KB) -> page fault.
__global__ __launch_bounds__(256) void k_prep(const float* __restrict__ W,
                                              uint4* __restrict__ Wfh, uint4* __restrict__ Wfl) {
    int tid = blockIdx.x * 256 + threadIdx.x;   // 0..2047
    if (tid >= 2048) return;
    int c = tid >> 9;                           // 0..3
    int tp = (tid >> 6) & 7;
    int lane = tid & 63;
    int f = tp * 16 + (lane & 15);
    int k = c * 32 + (lane >> 4) * 8;
    const float* wp = W + f * F + k;
    unsigned h[4], l[4];
#pragma unroll
    for (int p = 0; p < 4; p++) split2(wp[2 * p], wp[2 * p + 1], h[p], l[p]);
    Wfh[tid] = make_uint4(h[0], h[1], h[2], h[3]);
    Wfl[tid] = make_uint4(l[0], l[1], l[2], l[3]);
}

// ---------------------------------------------------------------- K1: in-degree histogram of dst
__global__ __launch_bounds__(256) void k_hist(const int* __restrict__ edge, int* __restrict__ cnt, int E) {
    int e = blockIdx.x * 256 + threadIdx.x;
    if (e < E) atomicAdd(&cnt[edge[E + e]], 1);
}

// ---------------------------------------------------------------- K2: y = x @ W^T via split-bf16 MFMA
// y = (x_hi+x_lo)(W_hi+W_lo)^T ~= hi*hi + hi*lo + lo*hi  (f32 accum; lo*lo ~2^-17 rel, dropped)
// 512 thr / 8 waves; block tile 128x128, K=128 in 4 chunks of 32.
// Wave w owns M-rows [16w,16w+16): A frag loaded global->reg (16 rows x 128B segments, coalesced),
// B frags ds_read_b128 lane-contiguous from pre-packed LDS. C/D: col=lane&15, row=(lane>>4)*4+r.
// Fused epilogue: ssum2[f] += sum_n y^2 ; wsum2[f] += sum_n cnt[n]*y^2
__global__ __launch_bounds__(512, 4) void k_gemm(const float* __restrict__ x,
                                                 const uint4* __restrict__ Wfh, const uint4* __restrict__ Wfl,
                                                 const int* __restrict__ cnt, float* __restrict__ y,
                                                 float* __restrict__ ssum2, float* __restrict__ wsum2, int N) {
    __shared__ uint4 Wh_s[2048];   // 32 KB  B-frags hi
    __shared__ uint4 Wl_s[2048];   // 32 KB  B-frags lo
    __shared__ float red_ss[F];
    __shared__ float red_ws[F];
    __shared__ int cntL[TM];

    int t = threadIdx.x;
    int lane = t & 63;
    int w = t >> 6;
    int n0 = blockIdx.x * TM;

    if (t < F) { red_ss[t] = 0.f; red_ws[t] = 0.f; }
    if (t < TM) { int n = n0 + t; cntL[t] = (n < N) ? cnt[n] : 0; }

    // stage both fragment planes: linear dest = wave-uniform base + lane*16
#pragma unroll
    for (int r = 0; r < 4; r++) {
        int off = (r * 512 + t) * 16;
        load_lds16((const char*)Wfh + off, (char*)Wh_s + off);
    }
#pragma unroll
    for (int r = 0; r < 4; r++) {
        int off = (r * 512 + t) * 16;
        load_lds16((const char*)Wfl + off, (char*)Wl_s + off);
    }

    int row = n0 + w * 16 + (lane & 15);
    if (row > N - 1) row = N - 1;                 // clamp: no fault, masked in epilogue
    const float* xr = x + (size_t)row * F + (lane >> 4) * 8;

    f32x4 acc[8];
#pragma unroll
    for (int i = 0; i < 8; i++) acc[i] = (f32x4){0.f, 0.f, 0.f, 0.f};

    float4 a0 = *(const float4*)xr;               // chunk 0 A-frag, issued before barrier
    float4 a1 = *(const float4*)(xr + 4);

    __syncthreads();

#pragma unroll
    for (int c = 0; c < 4; c++) {
        float4 na0, na1;
        if (c < 3) {                              // prefetch next chunk's A under this chunk's MFMAs
            na0 = *(const float4*)(xr + (c + 1) * 32);
            na1 = *(const float4*)(xr + (c + 1) * 32 + 4);
        }
        unsigned h[4], l[4];
        split2(a0.x, a0.y, h[0], l[0]);
        split2(a0.z, a0.w, h[1], l[1]);
        split2(a1.x, a1.y, h[2], l[2]);
        split2(a1.z, a1.w, h[3], l[3]);
        s16x8 a_hi = __builtin_bit_cast(s16x8, make_uint4(h[0], h[1], h[2], h[3]));
        s16x8 a_lo = __builtin_bit_cast(s16x8, make_uint4(l[0], l[1], l[2], l[3]));
#pragma unroll
        for (int tp = 0; tp < 8; tp++) {
            s16x8 bh = __builtin_bit_cast(s16x8, Wh_s[(c * 8 + tp) * 64 + lane]);
            s16x8 bl = __builtin_bit_cast(s16x8, Wl_s[(c * 8 + tp) * 64 + lane]);
            acc[tp] = __builtin_amdgcn_mfma_f32_16x16x32_bf16(a_hi, bh, acc[tp], 0, 0, 0);
            acc[tp] = __builtin_amdgcn_mfma_f32_16x16x32_bf16(a_lo, bh, acc[tp], 0, 0, 0);
            acc[tp] = __builtin_amdgcn_mfma_f32_16x16x32_bf16(a_hi, bl, acc[tp], 0, 0, 0);
        }
        if (c < 3) { a0 = na0; a1 = na1; }
    }

    // epilogue: store y + fused ssum2/wsum2
    int fb = lane & 15;
    int rg = lane >> 4;
#pragma unroll
    for (int tp = 0; tp < 8; tp++) {
        int f = tp * 16 + fb;
        float sv = 0.f, wv = 0.f;
#pragma unroll
        for (int r = 0; r < 4; r++) {
            int lr = w * 16 + rg * 4 + r;
            int n = n0 + lr;
            float v = acc[tp][r];
            if (n < N) {
                y[(size_t)n * F + f] = v;         // 16 lanes -> 64B contiguous per row
                sv += v * v;
                wv += (float)cntL[lr] * v * v;
            }
        }
        sv += __shfl_xor(sv, 16, 64); sv += __shfl_xor(sv, 32, 64);
        wv += __shfl_xor(wv, 16, 64); wv += __shfl_xor(wv, 32, 64);
        if (lane < 16) {
            atomicAdd(&red_ss[f], sv);
            atomicAdd(&red_ws[f], wv);
        }
    }
    __syncthreads();
    if (t < F) {
        atomicAdd(&ssum2[t], red_ss[t]);
        atomicAdd(&wsum2[t], red_ws[t]);
    }
}

// ---------------------------------------------------------------- K2b: all global scalar factors (f64)
__global__ __launch_bounds__(256) void k_scalars(const float* __restrict__ W, const float* __restrict__ a,
                                                 const float* __restrict__ ssum2, const float* __restrict__ wsum2,
                                                 float* __restrict__ s_arr, float* __restrict__ asrc,
                                                 float* __restrict__ adst, double* __restrict__ an_out) {
    int t = threadIdx.x;
    double av = (double)a[t];
    av *= av;
#pragma unroll
    for (int off = 32; off; off >>= 1) av += __shfl_down(av, off, 64);
    __shared__ double wred[4];
    if ((t & 63) == 0) wred[t >> 6] = av;
    __syncthreads();
    double an = fmax(sqrt(wred[0] + wred[1] + wred[2] + wred[3]), MIN_NORM_D);
    if (t == 0) an_out[0] = an;

    if (t < F) {
        double wn2 = 0.0;
        for (int k = 0; k < F; k++) { double w = (double)W[t * F + k]; wn2 += w * w; }
        double wn = fmax(sqrt(wn2), MIN_NORM_D);
        double mxnf = fmax(sqrt((double)ssum2[t]), MIN_NORM_D);
        double tt = tanh(mxnf / wn * atanh_clip(wn));
        double rn = fmax(tt, MIN_NORM_D);
        double pf = (rn > MAXNORM_D) ? MAXNORM_D / rn : 1.0;
        double pn = rn * pf;
        double s = (tt / mxnf) * pf * atanh_clip(pn) / pn;
        s_arr[t] = (float)s;

        double un_s = fmax(s * sqrt((double)DEG * (double)ssum2[t]), MIN_NORM_D);
        double th_s = tanh(un_s);
        double rn2 = fmax(th_s, MIN_NORM_D);
        double pf2 = (rn2 > MAXNORM_D) ? MAXNORM_D / rn2 : 1.0;
        double q_s = s * (th_s / un_s) * pf2;
        asrc[t] = (float)((double)a[t] * q_s);

        double un_d = fmax(s * sqrt((double)wsum2[t]), MIN_NORM_D);
        double th_d = tanh(un_d);
        double rn3 = fmax(th_d, MIN_NORM_D);
        double pf3 = (rn3 > MAXNORM_D) ? MAXNORM_D / rn3 : 1.0;
        double q_d = s * (th_d / un_d) * pf3;
        adst[t] = (float)((double)a[F + t] * q_d);
    }
}

// ---------------------------------------------------------------- K3: P[n]=dot(asrc,y[n,:]) Q[n]=dot(adst,y[n,:])
__global__ __launch_bounds__(256) void k_pq(const float* __restrict__ y, const float* __restrict__ asrc,
                                            const float* __restrict__ adst, float* __restrict__ P,
                                            float* __restrict__ Q, int N) {
    __shared__ float as4[F], ad4[F];
    int t = threadIdx.x;
    if (t < F) { as4[t] = asrc[t]; ad4[t] = adst[t]; }
    __syncthreads();
    int lane = t & 31;
    int n = blockIdx.x * 8 + (t >> 5);
    if (n < N) {
        float4 yv = *(const float4*)&y[(size_t)n * F + lane * 4];
        float4 av = *(const float4*)&as4[lane * 4];
        float4 bv = *(const float4*)&ad4[lane * 4];
        float p = yv.x * av.x + yv.y * av.y + yv.z * av.z + yv.w * av.w;
        float q = yv.x * bv.x + yv.y * bv.y + yv.z * bv.z + yv.w * bv.w;
#pragma unroll
        for (int off = 16; off; off >>= 1) {
            p += __shfl_down(p, off, 32);
            q += __shfl_down(q, off, 32);
        }
        if (lane == 0) { P[n] = p; Q[n] = q; }
    }
}

// ---------------------------------------------------------------- K4: ee_pre[e] = P[src]+Q[dst]; ||ee_pre||^2 (f64)
__global__ __launch_bounds__(256) void k_edge(const int* __restrict__ edge, const float* __restrict__ P,
                                              const float* __restrict__ Q, float* __restrict__ ee_pre,
                                              double* __restrict__ mxn2, int E) {
    int t = threadIdx.x;
    int e = blockIdx.x * 256 + t;
    double local = 0.0;
    if (e < E) {
        int s = edge[e];
        int d = edge[E + e];
        float v = P[s] + Q[d];
        ee_pre[e] = v;
        local = (double)v * (double)v;
    }
#pragma unroll
    for (int off = 32; off; off >>= 1) local += __shfl_down(local, off, 64);
    __shared__ double wsum[4];
    if ((t & 63) == 0) wsum[t >> 6] = local;
    __syncthreads();
    if (t == 0) atomicAdd(mxn2, wsum[0] + wsum[1] + wsum[2] + wsum[3]);
}

// ---------------------------------------------------------------- K5: per-node NORMALIZED edge weights
__global__ __launch_bounds__(256) void k_w(const float* __restrict__ ee_pre,
                                           const double* __restrict__ an_p, const double* __restrict__ mxn2_p,
                                           float* __restrict__ wn, int N) {
    __shared__ float gS;
    if (threadIdx.x == 0) {
        double an = an_p[0];
        double mxn = fmax(sqrt(mxn2_p[0]), MIN_NORM_D);
        double t2 = tanh(mxn / an * atanh_clip(an));
        double f2 = t2 / mxn;
        double rnp = fmax(t2, MIN_NORM_D);
        double pfp = (rnp > MAXNORM_D) ? MAXNORM_D / rnp : 1.0;
        double pnp = rnp * pfp;
        gS = (float)(f2 * pfp * atanh_clip(pnp) / pnp);
    }
    __syncthreads();
    float g = gS;
    int n = blockIdx.x * 256 + threadIdx.x;
    if (n < N) {
        float r[DEG];
        float rowsum = 0.f;
#pragma unroll
        for (int j = 0; j < DEG; j++) {
            float xg = g * ee_pre[n * DEG + j];
            float gl = 0.5f * xg * (1.f + erff(xg * 0.70710678f));
            float w = expf(-gl);
            r[j] = w;
            rowsum += w;
        }
        float inv = 1.f / rowsum;
#pragma unroll
        for (int j = 0; j < DEG; j++) wn[n * DEG + j] = r[j] * inv;
    }
}

// ---------------------------------------------------------------- K6: per-node aggregate + epilogue
__global__ __launch_bounds__(256) void k_agg(const int* __restrict__ edge, const float* __restrict__ y,
                                             const float* __restrict__ wn, const float* __restrict__ s_arr,
                                             float* __restrict__ out, int N, int E) {
    __shared__ float wsh[8 * DEG];
    __shared__ int dsh[8 * DEG];
    int t = threadIdx.x;
    int n_base = blockIdx.x * 8;

    if (t < 8 * DEG) {
        int n = n_base + t / DEG;
        float w = 0.f; int d = 0;
        if (n < N) {
            int e = n * DEG + (t % DEG);
            w = wn[e];
            d = edge[E + e];
        }
        wsh[t] = w;
        dsh[t] = d << 7;
    }
    __syncthreads();

    int grp = t >> 5;        // 0..7
    int lane = t & 31;
    int n = n_base + grp;
    if (n >= N) return;

    int fo = lane * 4;
    float4 acc = make_float4(0.f, 0.f, 0.f, 0.f);
#pragma unroll
    for (int j = 0; j < DEG; j++) {
        float w = wsh[grp * DEG + j];
        int d = dsh[grp * DEG + j];
        float4 yv = *(const float4*)&y[d + fo];
        acc.x = fmaf(w, yv.x, acc.x);
        acc.y = fmaf(w, yv.y, acc.y);
        acc.z = fmaf(w, yv.z, acc.z);
        acc.w = fmaf(w, yv.w, acc.w);
    }
    float4 s4 = *(const float4*)&s_arr[fo];
    float4 el;
    float hx = s4.x * acc.x; el.x = (hx > 0.f) ? hx : expm1f(hx);
    float hy = s4.y * acc.y; el.y = (hy > 0.f) ? hy : expm1f(hy);
    float hz = s4.z * acc.z; el.z = (hz > 0.f) ? hz : expm1f(hz);
    float hw = s4.w * acc.w; el.w = (hw > 0.f) ? hw : expm1f(hw);

    float ss = el.x * el.x + el.y * el.y + el.z * el.z + el.w * el.w;
#pragma unroll
    for (int off = 16; off; off >>= 1) ss += __shfl_xor(ss, off, 32);

    float un = fmaxf(sqrtf(ss), 1e-15f);
    float th = tanhf(un);
    float sc = th / un;                   // expmap0
    float rn = fmaxf(th, 1e-15f);
    if (rn > 0.996f) sc *= 0.996f / rn;   // proj
    float4 o = make_float4(el.x * sc, el.y * sc, el.z * sc, el.w * sc);
    *(float4*)&out[(size_t)n * F + fo] = o;
}

extern "C" void kernel_launch(void* const* d_in, const int* in_sizes, int n_in,
                              void* d_out, int out_size, void* d_ws, size_t ws_size,
                              hipStream_t stream) {
    const float* x = (const float*)d_in[0];
    const int* edge = (const int*)d_in[1];
    const float* W = (const float*)d_in[2];
    const float* a = (const float*)d_in[3];
    float* out = (float*)d_out;
    int N = in_sizes[0] / F;
    int E = in_sizes[1] / 2;

    char* ws = (char*)d_ws;
    size_t off = 0;
    float* y = (float*)(ws + off);       off += (size_t)N * F * 4;
    uint4* Wfh = (uint4*)(ws + off);     off += 2048 * 16;            // 32 KB B-frag hi
    uint4* Wfl = (uint4*)(ws + off);     off += 2048 * 16;            // 32 KB B-frag lo
    float* ee_pre = (float*)(ws + off);  off += (size_t)E * 4;
    float* wn = (float*)(ws + off);      off += (size_t)E * 4;
    float* P = (float*)(ws + off);       off += (size_t)N * 4;
    float* Q = (float*)(ws + off);       off += (size_t)N * 4;
    char* zbase = ws + off;
    int* cnt = (int*)(ws + off);         off += (size_t)N * 4;
    float* ssum2 = (float*)(ws + off);   off += 512;
    float* wsum2 = (float*)(ws + off);   off += 512;
    double* mxn2 = (double*)(ws + off);  off += 8;
    size_t zlen = (size_t)((ws + off) - zbase);
    double* an_p = (double*)(ws + off);  off += 8;
    float* s_arr = (float*)(ws + off);   off += 512;
    float* asrc = (float*)(ws + off);    off += 512;
    float* adst = (float*)(ws + off);    off += 512;

    hipMemsetAsync(zbase, 0, zlen, stream);
    k_prep<<<8, 256, 0, stream>>>(W, Wfh, Wfl);
    k_hist<<<(E + 255) / 256, 256, 0, stream>>>(edge, cnt, E);
    k_gemm<<<(N + TM - 1) / TM, 512, 0, stream>>>(x, Wfh, Wfl, cnt, y, ssum2, wsum2, N);
    k_scalars<<<1, 256, 0, stream>>>(W, a, ssum2, wsum2, s_arr, asrc, adst, an_p);
    k_pq<<<(N + 7) / 8, 256, 0, stream>>>(y, asrc, adst, P, Q, N);
    k_edge<<<(E + 255) / 256, 256, 0, stream>>>(edge, P, Q, ee_pre, mxn2, E);
    k_w<<<(N + 255) / 256, 256, 0, stream>>>(ee_pre, an_p, mxn2, wn, N);
    k_agg<<<(N + 7) / 8, 256, 0, stream>>>(edge, y, wn, s_arr, out, N, E);
}